// Round 1
// baseline (20360.358 us; speedup 1.0000x reference)
//
#include <hip/hip_runtime.h>

#define NB 256        // threads per block (one batch row per thread)
#define HID 64
#define TSTEPS 64

__device__ __forceinline__ float fast_exp2(float x) {
#if __has_builtin(__builtin_amdgcn_exp2f)
    return __builtin_amdgcn_exp2f(x);
#else
    return exp2f(x);
#endif
}
__device__ __forceinline__ float fast_rcp(float x) {
#if __has_builtin(__builtin_amdgcn_rcpf)
    return __builtin_amdgcn_rcpf(x);
#else
    return 1.0f / x;
#endif
}

#define LOG2E 1.44269504088896341f

__device__ __forceinline__ float sigmoidf_(float x) {
    // 1/(1+e^-x); saturates correctly at +/-inf (rcp(inf)=0)
    return fast_rcp(1.0f + fast_exp2(-LOG2E * x));
}
__device__ __forceinline__ float tanhf_(float x) {
    // 1 - 2/(e^{2x}+1); exp2 overflow -> inf -> rcp -> 0 -> +1 (safe)
    return 1.0f - 2.0f * fast_rcp(1.0f + fast_exp2(2.0f * LOG2E * x));
}

struct SmallTabs {
    float  m0w[64], m1w[64], m1b[64], m2w[64], m3w[64], m3b[64], m4w[64];
    float4 wib[64];    // (Wih[j], Wih[64+j], Wih[128+j], Wih[192+j])
    float4 gbias[64];  // (Bih+Bhh) interleaved i,f,g,o per unit j
    float  wp[5 * 64];
    float  bp[5];
    float  m0b, m2b, m4b;
};

__global__ __launch_bounds__(NB, 2) void moglstm_kernel(
    const float* __restrict__ x,
    const float* __restrict__ W1, const float* __restrict__ B1,
    const float* __restrict__ W2, const float* __restrict__ B2,
    const float* __restrict__ W3, const float* __restrict__ B3,
    const float* __restrict__ W4, const float* __restrict__ B4,
    const float* __restrict__ M0w, const float* __restrict__ M0b,
    const float* __restrict__ M1w, const float* __restrict__ M1b,
    const float* __restrict__ M2w, const float* __restrict__ M2b,
    const float* __restrict__ M3w, const float* __restrict__ M3b,
    const float* __restrict__ M4w, const float* __restrict__ M4b,
    const float* __restrict__ Wih, const float* __restrict__ Bih,
    const float* __restrict__ Whh, const float* __restrict__ Bhh,
    const float* __restrict__ Wp,  const float* __restrict__ Bp,
    float* __restrict__ out)
{
    // 64 KiB union: phase A = W1..W4 (each 64x64 row-major, viewed as float4);
    //               phase B = Whh interleaved: entry j*64+k = (i,f,g,o) weight at (unit j, k)
    __shared__ float4 sW4[4096];
    __shared__ SmallTabs st;

    const int tid = threadIdx.x;
    const long b = (long)blockIdx.x * NB + tid;

    // ---------------- stage small tables + MLP weights ----------------
    if (tid < 64) {
        st.m0w[tid] = M0w[tid]; st.m1w[tid] = M1w[tid]; st.m1b[tid] = M1b[tid];
        st.m2w[tid] = M2w[tid]; st.m3w[tid] = M3w[tid]; st.m3b[tid] = M3b[tid];
        st.m4w[tid] = M4w[tid];
        st.wib[tid]   = make_float4(Wih[tid], Wih[64 + tid], Wih[128 + tid], Wih[192 + tid]);
        st.gbias[tid] = make_float4(Bih[tid] + Bhh[tid],
                                    Bih[64 + tid] + Bhh[64 + tid],
                                    Bih[128 + tid] + Bhh[128 + tid],
                                    Bih[192 + tid] + Bhh[192 + tid]);
    }
    for (int i = tid; i < 320; i += NB) st.wp[i] = Wp[i];
    if (tid < 5) st.bp[tid] = Bp[tid];
    if (tid == 0) { st.m0b = M0b[0]; st.m2b = M2b[0]; st.m4b = M4b[0]; }
    {
        const float4* w1 = (const float4*)W1;
        const float4* w2 = (const float4*)W2;
        const float4* w3 = (const float4*)W3;
        const float4* w4 = (const float4*)W4;
        for (int i = tid; i < 1024; i += NB) sW4[i]        = w1[i];
        for (int i = tid; i < 1024; i += NB) sW4[1024 + i] = w2[i];
        for (int i = tid; i < 1024; i += NB) sW4[2048 + i] = w3[i];
        for (int i = tid; i < 1024; i += NB) sW4[3072 + i] = w4[i];
    }
    __syncthreads();

    // ---------------- MLP stem (4x Linear(64->64)+ReLU) ----------------
    float va[HID], vb[HID];
    {
        const float4* xrow = (const float4*)(x + b * HID);
        #pragma unroll
        for (int k4 = 0; k4 < 16; ++k4) {
            float4 v = xrow[k4];
            va[4 * k4 + 0] = v.x; va[4 * k4 + 1] = v.y;
            va[4 * k4 + 2] = v.z; va[4 * k4 + 3] = v.w;
        }
    }
    // per-thread time sequence; read with dynamic t later -> lives in scratch (coalesced)
    float xseq[TSTEPS];

#define MLP_LAYER(SRC, DST, BASE, BPTR)                              \
    _Pragma("unroll")                                                \
    for (int j = 0; j < 64; ++j) {                                   \
        float acc = BPTR[j];                                         \
        _Pragma("unroll")                                            \
        for (int k4 = 0; k4 < 16; ++k4) {                            \
            float4 w = sW4[(BASE) + j * 16 + k4];                    \
            acc += w.x * SRC[4 * k4 + 0] + w.y * SRC[4 * k4 + 1]     \
                 + w.z * SRC[4 * k4 + 2] + w.w * SRC[4 * k4 + 3];    \
        }                                                            \
        DST[j] = fmaxf(acc, 0.0f);                                   \
    }

    MLP_LAYER(va, vb, 0, B1)
    MLP_LAYER(vb, va, 1024, B2)
    MLP_LAYER(va, vb, 2048, B3)
    MLP_LAYER(vb, xseq, 3072, B4)
#undef MLP_LAYER

    __syncthreads();  // everyone done reading phase-A LDS

    // ---------------- re-stage LDS with interleaved Whh ----------------
    for (int i = tid; i < 4096; i += NB) {
        int j = i >> 6, k = i & 63;
        sW4[i] = make_float4(Whh[j * 64 + k],
                             Whh[(64 + j) * 64 + k],
                             Whh[(128 + j) * 64 + k],
                             Whh[(192 + j) * 64 + k]);
    }
    __syncthreads();

    // ---------------- mogrifier-LSTM recurrence ----------------
    float h[HID], c[HID], hn[HID];
    #pragma unroll
    for (int k = 0; k < HID; ++k) { h[k] = 0.0f; c[k] = 0.0f; }

    #pragma unroll 1
    for (int t = 0; t < TSTEPS; ++t) {
        __syncthreads();  // lockstep waves -> shared I$ stream through the big body
        float xt = xseq[t];

        // mogrify step 0: xt *= 2*sig(h.M0w + m0b)
        float s0 = st.m0b;
        #pragma unroll
        for (int k = 0; k < HID; ++k) s0 += st.m0w[k] * h[k];
        xt *= 2.0f * sigmoidf_(s0);

        // mogrify step 1: h *= 2*sig(xt*M1w + M1b)
        #pragma unroll
        for (int k = 0; k < HID; ++k) h[k] *= 2.0f * sigmoidf_(xt * st.m1w[k] + st.m1b[k]);

        // mogrify step 2
        float s2 = st.m2b;
        #pragma unroll
        for (int k = 0; k < HID; ++k) s2 += st.m2w[k] * h[k];
        xt *= 2.0f * sigmoidf_(s2);

        // mogrify step 3
        #pragma unroll
        for (int k = 0; k < HID; ++k) h[k] *= 2.0f * sigmoidf_(xt * st.m3w[k] + st.m3b[k]);

        // mogrify step 4
        float s4 = st.m4b;
        #pragma unroll
        for (int k = 0; k < HID; ++k) s4 += st.m4w[k] * h[k];
        xt *= 2.0f * sigmoidf_(s4);

        // LSTM cell: gates = xt*Wih + Bih + Bhh + Whh @ h ; order i,f,g,o
        #pragma unroll
        for (int j = 0; j < 64; ++j) {
            float4 wib = st.wib[j];
            float4 gb  = st.gbias[j];
            float ai = gb.x + xt * wib.x;
            float af = gb.y + xt * wib.y;
            float ag = gb.z + xt * wib.z;
            float ao = gb.w + xt * wib.w;
            #pragma unroll
            for (int k = 0; k < HID; ++k) {
                float4 w = sW4[(j << 6) + k];  // broadcast ds_read_b128
                float hk = h[k];
                ai += w.x * hk; af += w.y * hk; ag += w.z * hk; ao += w.w * hk;
            }
            float cj = sigmoidf_(af) * c[j] + sigmoidf_(ai) * tanhf_(ag);
            c[j]  = cj;
            hn[j] = sigmoidf_(ao) * tanhf_(cj);
        }
        #pragma unroll
        for (int k = 0; k < HID; ++k) h[k] = hn[k];
    }

    // ---------------- projection: out = h @ Wp.T + Bp ----------------
    #pragma unroll
    for (int p = 0; p < 5; ++p) {
        float acc = st.bp[p];
        #pragma unroll
        for (int k = 0; k < HID; ++k) acc += st.wp[p * 64 + k] * h[k];
        out[b * 5 + p] = acc;
    }
}

extern "C" void kernel_launch(void* const* d_in, const int* in_sizes, int n_in,
                              void* d_out, int out_size, void* d_ws, size_t ws_size,
                              hipStream_t stream) {
    const float* x   = (const float*)d_in[0];
    const float* W1  = (const float*)d_in[1];
    const float* B1  = (const float*)d_in[2];
    const float* W2  = (const float*)d_in[3];
    const float* B2  = (const float*)d_in[4];
    const float* W3  = (const float*)d_in[5];
    const float* B3  = (const float*)d_in[6];
    const float* W4  = (const float*)d_in[7];
    const float* B4  = (const float*)d_in[8];
    const float* M0w = (const float*)d_in[9];
    const float* M0b = (const float*)d_in[10];
    const float* M1w = (const float*)d_in[11];
    const float* M1b = (const float*)d_in[12];
    const float* M2w = (const float*)d_in[13];
    const float* M2b = (const float*)d_in[14];
    const float* M3w = (const float*)d_in[15];
    const float* M3b = (const float*)d_in[16];
    const float* M4w = (const float*)d_in[17];
    const float* M4b = (const float*)d_in[18];
    const float* Wih = (const float*)d_in[19];
    const float* Bih = (const float*)d_in[20];
    const float* Whh = (const float*)d_in[21];
    const float* Bhh = (const float*)d_in[22];
    const float* Wp  = (const float*)d_in[23];
    const float* Bp  = (const float*)d_in[24];

    int B = in_sizes[0] / HID;       // 262144
    int nblocks = B / NB;            // 1024 (B divisible by 256)

    hipLaunchKernelGGL(moglstm_kernel, dim3(nblocks), dim3(NB), 0, stream,
                       x, W1, B1, W2, B2, W3, B3, W4, B4,
                       M0w, M0b, M1w, M1b, M2w, M2b, M3w, M3b, M4w, M4b,
                       Wih, Bih, Whh, Bhh, Wp, Bp, (float*)d_out);
}

// Round 2
// 3143.430 us; speedup vs baseline: 6.4771x; 6.4771x over previous
//
#include <hip/hip_runtime.h>

#define NTHREADS 512
#define ROWS_PB  128     // rows per block
#define NW       8       // waves per block
#define HID      64
#define TSTEPS   64

typedef __attribute__((ext_vector_type(8))) short bf16x8;   // 8 bf16 = 4 VGPR
typedef __attribute__((ext_vector_type(4))) float f32x4;    // MFMA C/D

__device__ __forceinline__ float fast_exp2(float x) { return __builtin_amdgcn_exp2f(x); }
__device__ __forceinline__ float fast_rcp(float x)  { return __builtin_amdgcn_rcpf(x); }
#define LOG2E 1.44269504088896341f
__device__ __forceinline__ float sigmoidf_(float x) { return fast_rcp(1.0f + fast_exp2(-LOG2E * x)); }
__device__ __forceinline__ float tanhf_(float x)    { return 1.0f - 2.0f * fast_rcp(1.0f + fast_exp2(2.0f * LOG2E * x)); }

__device__ __forceinline__ unsigned short f2bf(float f) {   // RNE fp32->bf16
    unsigned u = __float_as_uint(f);
    u = u + 0x7fffu + ((u >> 16) & 1u);
    return (unsigned short)(u >> 16);
}
__device__ __forceinline__ float bf2f(unsigned short h) {
    return __uint_as_float(((unsigned)h) << 16);
}

// LDS carve (bytes):
//   [0      .. 32768)  sWhi  : Whh hi-frags, frag-order [tile16][kc2][lane64] x 16B
//   [32768  .. 65536)  sWlo  : Whh lo-frags
//   (region A above doubles as stem ping buffer: 128x68 f32 = 34816 B)
//   [65536  ..100352)  sXseq : [128 rows][68] f32  (stem pong buffer, then xseq[row][t])
//   [100352 ..135168)  sTr   : 8 waves x [16 rows][68] f32 transpose buffers
//   [135168 ..138272)  sMog  : m0w,m1w,m1b,m2w,m3w,m3b,m4w (7x64), wp(320), bp(5)
#define SMEM_BYTES 138272
#define MOG_M0W 0
#define MOG_M1W 64
#define MOG_M1B 128
#define MOG_M2W 192
#define MOG_M3W 256
#define MOG_M3B 320
#define MOG_M4W 384
#define MOG_WP  448
#define MOG_BP  768

__global__ __launch_bounds__(NTHREADS, 2) void moglstm_mfma(
    const float* __restrict__ x,
    const float* __restrict__ W1, const float* __restrict__ B1,
    const float* __restrict__ W2, const float* __restrict__ B2,
    const float* __restrict__ W3, const float* __restrict__ B3,
    const float* __restrict__ W4, const float* __restrict__ B4,
    const float* __restrict__ M0w, const float* __restrict__ M0b,
    const float* __restrict__ M1w, const float* __restrict__ M1b,
    const float* __restrict__ M2w, const float* __restrict__ M2b,
    const float* __restrict__ M3w, const float* __restrict__ M3b,
    const float* __restrict__ M4w, const float* __restrict__ M4b,
    const float* __restrict__ Wih, const float* __restrict__ Bih,
    const float* __restrict__ Whh, const float* __restrict__ Bhh,
    const float* __restrict__ Wp,  const float* __restrict__ Bp,
    float* __restrict__ out)
{
    __shared__ __align__(16) char smem[SMEM_BYTES];
    bf16x8* sWhi  = (bf16x8*)(smem);
    bf16x8* sWlo  = (bf16x8*)(smem + 32768);
    float*  sXseq = (float*)(smem + 65536);
    float*  sTr   = (float*)(smem + 100352);
    float*  sMog  = (float*)(smem + 135168);

    const int tid = threadIdx.x;
    const long rowbase = (long)blockIdx.x * ROWS_PB;

    // ================= MLP stem: 4x Linear(64->64)+ReLU =================
    // ping-pong: x -> bufB, L1: B->A, L2: A->B, L3: B->A, L4: A->B(=xseq)
    float* bufA = (float*)smem;   // 8704 floats needed, region A has 16384
    float* bufB = sXseq;

    for (int i = tid; i < ROWS_PB * 16; i += NTHREADS) {
        int r = i >> 4, c4 = i & 15;
        float4 v = ((const float4*)x)[(rowbase + r) * 16 + c4];
        *(float4*)&bufB[r * 68 + c4 * 4] = v;
    }
    __syncthreads();

    const int qr = tid & 127;    // row within block
    const int qq = tid >> 7;     // quarter: computes units 16q..16q+15
    float rin[HID];

#define STEM_LAYER(SRC, DST, W, Bv)                                            \
    {                                                                          \
        _Pragma("unroll")                                                      \
        for (int k4 = 0; k4 < 16; ++k4) {                                      \
            float4 v = *(const float4*)&SRC[qr * 68 + k4 * 4];                 \
            rin[4*k4+0] = v.x; rin[4*k4+1] = v.y;                              \
            rin[4*k4+2] = v.z; rin[4*k4+3] = v.w;                              \
        }                                                                      \
        _Pragma("unroll")                                                      \
        for (int jj4 = 0; jj4 < 4; ++jj4) {                                    \
            float accv[4];                                                     \
            _Pragma("unroll")                                                  \
            for (int e = 0; e < 4; ++e) {                                      \
                int j = qq * 16 + jj4 * 4 + e;                                 \
                float a = Bv[j];                                               \
                const float4* wr = (const float4*)&W[j * 64];                  \
                _Pragma("unroll")                                              \
                for (int k4 = 0; k4 < 16; ++k4) {                              \
                    float4 wv = wr[k4];                                        \
                    a += wv.x*rin[4*k4] + wv.y*rin[4*k4+1]                     \
                       + wv.z*rin[4*k4+2] + wv.w*rin[4*k4+3];                  \
                }                                                              \
                accv[e] = fmaxf(a, 0.0f);                                      \
            }                                                                  \
            *(float4*)&DST[qr * 68 + qq * 16 + jj4 * 4] =                      \
                make_float4(accv[0], accv[1], accv[2], accv[3]);               \
        }                                                                      \
        __syncthreads();                                                       \
    }

    STEM_LAYER(bufB, bufA, W1, B1)
    STEM_LAYER(bufA, bufB, W2, B2)
    STEM_LAYER(bufB, bufA, W3, B3)
    STEM_LAYER(bufA, bufB, W4, B4)   // final: sXseq[row][t]
#undef STEM_LAYER

    // ============ stage Whh split-bf16 fragments (frag order) ============
    // frag(tile,kc,lane): tile=(gi<<2)|ub, lane=(g<<4)|n
    //   element j = Whh[gi*64 + 4n + ub][kc*32 + g*8 + j]
    for (int Gi = tid; Gi < 2048; Gi += NTHREADS) {
        int lane = Gi & 63, kc = (Gi >> 6) & 1, tt = Gi >> 7;
        int gi = tt >> 2, ub = tt & 3, n = lane & 15, g = lane >> 4;
        const float* wsrc = &Whh[(gi * 64 + 4 * n + ub) * 64 + kc * 32 + g * 8];
        bf16x8 hi8, lo8;
        #pragma unroll
        for (int j = 0; j < 8; ++j) {
            float w = wsrc[j];
            unsigned short hb = f2bf(w);
            hi8[j] = (short)hb;
            lo8[j] = (short)f2bf(w - bf2f(hb));
        }
        sWhi[Gi] = hi8;
        sWlo[Gi] = lo8;
    }
    if (tid < 64) {
        sMog[MOG_M0W + tid] = M0w[tid];
        sMog[MOG_M1W + tid] = M1w[tid];
        sMog[MOG_M1B + tid] = M1b[tid];
        sMog[MOG_M2W + tid] = M2w[tid];
        sMog[MOG_M3W + tid] = M3w[tid];
        sMog[MOG_M3B + tid] = M3b[tid];
        sMog[MOG_M4W + tid] = M4w[tid];
    }
    for (int i = tid; i < 320; i += NTHREADS) sMog[MOG_WP + i] = Wp[i];
    if (tid < 5) sMog[MOG_BP + tid] = Bp[tid];

    // per-lane invariants (D-layout: lane = (g'<<4)|n)
    const int lane = tid & 63;
    const int wv   = tid >> 6;      // wave 0..7 -> rows wv*16..+15
    const int g_   = lane >> 4;     // group (A: k-chunk owner / D: row-quad)
    const int rr   = lane & 15;     // A: row / D: n (unit nibble)

    float wib_r[4][4], gb_r[4][4];
    #pragma unroll
    for (int gi = 0; gi < 4; ++gi)
        #pragma unroll
        for (int ub = 0; ub < 4; ++ub) {
            int rowg = gi * 64 + 4 * rr + ub;
            wib_r[gi][ub] = Wih[rowg];
            gb_r[gi][ub]  = Bih[rowg] + Bhh[rowg];
        }
    const float m0b_s = M0b[0], m2b_s = M2b[0], m4b_s = M4b[0];
    __syncthreads();

    // ===================== mogrifier-LSTM recurrence =====================
    // h: fp32, A-frag lane layout: lane(g_,rr) holds row rr,
    //    units {c*32 + 8*g_ + j : c in 0..1, j in 0..7} as h[c*8+j]
    // c: fp32, D layout: lane(g_,rr=n) holds units 4n+ub, rows 4g_+e as c[ub*4+e]
    float h[16], c[16];
    #pragma unroll
    for (int i = 0; i < 16; ++i) { h[i] = 0.0f; c[i] = 0.0f; }

    float* trw = &sTr[wv * 16 * 68];
    const float* xrow = &sXseq[(wv * 16 + rr) * 68];

    f32x4 acc[4][4];

#define MOG_DOT(VOFF, BIAS)                                                    \
    {                                                                          \
        float p = 0.0f;                                                        \
        _Pragma("unroll")                                                      \
        for (int cc = 0; cc < 2; ++cc) {                                       \
            _Pragma("unroll")                                                  \
            for (int q4 = 0; q4 < 2; ++q4) {                                   \
                float4 mv = *(const float4*)&sMog[(VOFF) + cc*32 + g_*8 + q4*4]; \
                int bse = cc * 8 + q4 * 4;                                     \
                p += mv.x*h[bse+0] + mv.y*h[bse+1] + mv.z*h[bse+2] + mv.w*h[bse+3]; \
            }                                                                  \
        }                                                                      \
        p += __shfl_xor(p, 16);                                                \
        p += __shfl_xor(p, 32);                                                \
        xt *= 2.0f * sigmoidf_(p + (BIAS));                                    \
    }

#define MOG_SCALE(WOFF, BOFF)                                                  \
    {                                                                          \
        _Pragma("unroll")                                                      \
        for (int cc = 0; cc < 2; ++cc) {                                       \
            _Pragma("unroll")                                                  \
            for (int q4 = 0; q4 < 2; ++q4) {                                   \
                float4 wv4 = *(const float4*)&sMog[(WOFF) + cc*32 + g_*8 + q4*4]; \
                float4 bv4 = *(const float4*)&sMog[(BOFF) + cc*32 + g_*8 + q4*4]; \
                int bse = cc * 8 + q4 * 4;                                     \
                h[bse+0] *= 2.0f * sigmoidf_(xt * wv4.x + bv4.x);              \
                h[bse+1] *= 2.0f * sigmoidf_(xt * wv4.y + bv4.y);              \
                h[bse+2] *= 2.0f * sigmoidf_(xt * wv4.z + bv4.z);              \
                h[bse+3] *= 2.0f * sigmoidf_(xt * wv4.w + bv4.w);              \
            }                                                                  \
        }                                                                      \
    }

    #pragma unroll 1
    for (int t = 0; t < TSTEPS; ++t) {
        float xt = xrow[t];

        // ---- mogrify (fp32) ----
        MOG_DOT(MOG_M0W, m0b_s)
        MOG_SCALE(MOG_M1W, MOG_M1B)
        MOG_DOT(MOG_M2W, m2b_s)
        MOG_SCALE(MOG_M3W, MOG_M3B)
        MOG_DOT(MOG_M4W, m4b_s)

        // ---- A-fragments: h -> split bf16 ----
        bf16x8 ahi[2], alo[2];
        #pragma unroll
        for (int cc = 0; cc < 2; ++cc)
            #pragma unroll
            for (int j = 0; j < 8; ++j) {
                float v = h[cc * 8 + j];
                unsigned short hb = f2bf(v);
                ahi[cc][j] = (short)hb;
                alo[cc][j] = (short)f2bf(v - bf2f(hb));
            }

        // ---- xt per D-row ----
        float xt4[4];
        #pragma unroll
        for (int e = 0; e < 4; ++e) xt4[e] = __shfl(xt, 4 * g_ + e, 64);

        // ---- C init: bias + xt*Wih (fp32) ----
        #pragma unroll
        for (int gi = 0; gi < 4; ++gi)
            #pragma unroll
            for (int ub = 0; ub < 4; ++ub)
                #pragma unroll
                for (int e = 0; e < 4; ++e)
                    acc[gi][ub][e] = gb_r[gi][ub] + xt4[e] * wib_r[gi][ub];

        // ---- gates += H @ Whh^T  (split bf16: Whi*hhi + Whi*hlo + Wlo*hhi) ----
        #pragma unroll
        for (int tt = 0; tt < 16; ++tt) {
            const int gi = tt >> 2, ub = tt & 3;
            bf16x8 w0 = sWhi[(tt * 2 + 0) * 64 + lane];
            bf16x8 w1 = sWhi[(tt * 2 + 1) * 64 + lane];
            bf16x8 l0 = sWlo[(tt * 2 + 0) * 64 + lane];
            bf16x8 l1 = sWlo[(tt * 2 + 1) * 64 + lane];
            f32x4 d = acc[gi][ub];
            d = __builtin_amdgcn_mfma_f32_16x16x32_bf16(ahi[0], w0, d, 0, 0, 0);
            d = __builtin_amdgcn_mfma_f32_16x16x32_bf16(ahi[1], w1, d, 0, 0, 0);
            d = __builtin_amdgcn_mfma_f32_16x16x32_bf16(alo[0], w0, d, 0, 0, 0);
            d = __builtin_amdgcn_mfma_f32_16x16x32_bf16(alo[1], w1, d, 0, 0, 0);
            d = __builtin_amdgcn_mfma_f32_16x16x32_bf16(ahi[0], l0, d, 0, 0, 0);
            d = __builtin_amdgcn_mfma_f32_16x16x32_bf16(ahi[1], l1, d, 0, 0, 0);
            acc[gi][ub] = d;
        }

        // ---- activations (D layout), c update, h_new -> transpose buffer ----
        #pragma unroll
        for (int e = 0; e < 4; ++e) {
            float hn4[4];
            #pragma unroll
            for (int ub = 0; ub < 4; ++ub) {
                float iv = acc[0][ub][e], fv = acc[1][ub][e];
                float gv = acc[2][ub][e], ov = acc[3][ub][e];
                float cc = sigmoidf_(fv) * c[ub * 4 + e] + sigmoidf_(iv) * tanhf_(gv);
                c[ub * 4 + e] = cc;
                hn4[ub] = sigmoidf_(ov) * tanhf_(cc);
            }
            // row 4g_+e, units 4rr..4rr+3
            *(float4*)&trw[(4 * g_ + e) * 68 + 4 * rr] =
                make_float4(hn4[0], hn4[1], hn4[2], hn4[3]);
        }

        // ---- read h back in A layout (wave-private: lgkmcnt only) ----
        #pragma unroll
        for (int cc = 0; cc < 2; ++cc) {
            float4 v0 = *(const float4*)&trw[rr * 68 + cc * 32 + g_ * 8];
            float4 v1 = *(const float4*)&trw[rr * 68 + cc * 32 + g_ * 8 + 4];
            h[cc*8+0] = v0.x; h[cc*8+1] = v0.y; h[cc*8+2] = v0.z; h[cc*8+3] = v0.w;
            h[cc*8+4] = v1.x; h[cc*8+5] = v1.y; h[cc*8+6] = v1.z; h[cc*8+7] = v1.w;
        }
    }

    // ===================== projection: out = h @ Wp^T + Bp =====================
    #pragma unroll
    for (int p = 0; p < 5; ++p) {
        float ap = 0.0f;
        #pragma unroll
        for (int cc = 0; cc < 2; ++cc) {
            #pragma unroll
            for (int q4 = 0; q4 < 2; ++q4) {
                float4 wv4 = *(const float4*)&sMog[MOG_WP + p * 64 + cc * 32 + g_ * 8 + q4 * 4];
                int bse = cc * 8 + q4 * 4;
                ap += wv4.x*h[bse+0] + wv4.y*h[bse+1] + wv4.z*h[bse+2] + wv4.w*h[bse+3];
            }
        }
        ap += __shfl_xor(ap, 16);
        ap += __shfl_xor(ap, 32);
        if (g_ == 0)
            out[(rowbase + wv * 16 + rr) * 5 + p] = ap + sMog[MOG_BP + p];
    }
}

extern "C" void kernel_launch(void* const* d_in, const int* in_sizes, int n_in,
                              void* d_out, int out_size, void* d_ws, size_t ws_size,
                              hipStream_t stream) {
    const float* x   = (const float*)d_in[0];
    const float* W1  = (const float*)d_in[1];
    const float* B1  = (const float*)d_in[2];
    const float* W2  = (const float*)d_in[3];
    const float* B2  = (const float*)d_in[4];
    const float* W3  = (const float*)d_in[5];
    const float* B3  = (const float*)d_in[6];
    const float* W4  = (const float*)d_in[7];
    const float* B4  = (const float*)d_in[8];
    const float* M0w = (const float*)d_in[9];
    const float* M0b = (const float*)d_in[10];
    const float* M1w = (const float*)d_in[11];
    const float* M1b = (const float*)d_in[12];
    const float* M2w = (const float*)d_in[13];
    const float* M2b = (const float*)d_in[14];
    const float* M3w = (const float*)d_in[15];
    const float* M3b = (const float*)d_in[16];
    const float* M4w = (const float*)d_in[17];
    const float* M4b = (const float*)d_in[18];
    const float* Wih = (const float*)d_in[19];
    const float* Bih = (const float*)d_in[20];
    const float* Whh = (const float*)d_in[21];
    const float* Bhh = (const float*)d_in[22];
    const float* Wp  = (const float*)d_in[23];
    const float* Bp  = (const float*)d_in[24];

    int B = in_sizes[0] / HID;          // 262144
    int nblocks = B / ROWS_PB;          // 2048

    hipLaunchKernelGGL(moglstm_mfma, dim3(nblocks), dim3(NTHREADS), 0, stream,
                       x, W1, B1, W2, B2, W3, B3, W4, B4,
                       M0w, M0b, M1w, M1b, M2w, M2b, M3w, M3b, M4w, M4b,
                       Wih, Bih, Whh, Bhh, Wp, Bp, (float*)d_out);
}